// Round 1
// baseline (446.190 us; speedup 1.0000x reference)
//
#include <hip/hip_runtime.h>
#include <cstddef>

#define NN 8192
#define CC 128

// ---- bf16 pack helpers ----
static __device__ inline unsigned f2bf_pack(float a, float b) {
  unsigned ua = __builtin_bit_cast(unsigned, a);
  ua += 0x7fffu + ((ua >> 16) & 1u);
  unsigned ub = __builtin_bit_cast(unsigned, b);
  ub += 0x7fffu + ((ub >> 16) & 1u);
  return (ua >> 16) | (ub & 0xffff0000u);
}
static __device__ inline float bf_lo(unsigned u) { return __builtin_bit_cast(float, u << 16); }
static __device__ inline float bf_hi(unsigned u) { return __builtin_bit_cast(float, u & 0xffff0000u); }

// ---- async global->LDS (16B per lane, no VGPR transit) ----
typedef const __attribute__((address_space(1))) void gvoid_t;
typedef __attribute__((address_space(3))) void lvoid_t;
static __device__ inline void glds16(const float* g, float* l) {
  __builtin_amdgcn_global_load_lds((gvoid_t*)g, (lvoid_t*)l, 16, 0, 0);
}

// ---------------- CSR build ----------------

__global__ __launch_bounds__(256) void count_deg_int_k(const int* __restrict__ dst, int* degi, int E) {
  int i = blockIdx.x * 256 + threadIdx.x;
  if (i < E) atomicAdd(&degi[dst[i]], 1);
}

__global__ __launch_bounds__(256) void dinv_k(const int* __restrict__ degi, float* __restrict__ dinv, int n) {
  int i = blockIdx.x * 256 + threadIdx.x;
  if (i < n) dinv[i] = rsqrtf((float)(degi[i] + 1));
}

__global__ __launch_bounds__(256) void scan_k(const int* __restrict__ degi, int* __restrict__ rowstart,
                                              int* __restrict__ cursor) {
  __shared__ int partial[256];
  int t = threadIdx.x;
  int base = t * 32;
  int local[32];
  int s = 0;
#pragma unroll
  for (int i = 0; i < 32; ++i) { local[i] = s; s += degi[base + i]; }
  partial[t] = s;
  __syncthreads();
  for (int off = 1; off < 256; off <<= 1) {
    int v = (t >= off) ? partial[t - off] : 0;
    __syncthreads();
    partial[t] += v;
    __syncthreads();
  }
  int offset = partial[t] - s;
#pragma unroll
  for (int i = 0; i < 32; ++i) {
    rowstart[base + i] = offset + local[i];
    cursor[base + i] = offset + local[i];
  }
  if (t == 255) rowstart[NN] = offset + s;
}

__global__ __launch_bounds__(256) void bucket_k(const int* __restrict__ src, const int* __restrict__ dst,
    int* __restrict__ cursor, int* __restrict__ col, int E) {
  int e = blockIdx.x * 256 + threadIdx.x;
  if (e >= E) return;
  int d = dst[e];
  int pos = atomicAdd(&cursor[d], 1);
  col[pos] = src[e];
}

// h1 = dd*(sum_in xws[s] + xws[d]) + conv_b + x   where xws = (x@W)*dinv[row]
__global__ __launch_bounds__(256) void gather_k(const int* __restrict__ rowstart, const int* __restrict__ col,
    const float* __restrict__ xws, const float* __restrict__ dinv, const float* __restrict__ cb,
    const float* __restrict__ x, float* __restrict__ h1) {
  int d = blockIdx.x * 2 + (threadIdx.x >> 7);
  int c = threadIdx.x & 127;
  int j0 = rowstart[d], j1 = rowstart[d + 1];
  float dd = dinv[d];
  float sum = 0.f;
  float v = 0.f;
  if (j0 < j1) v = xws[(size_t)col[j0] * CC + c];
  for (int j = j0; j < j1; ++j) {
    float v_next = 0.f;
    if (j + 1 < j1) v_next = xws[(size_t)col[j + 1] * CC + c];
    sum += v;
    v = v_next;
  }
  int idx = d * CC + c;
  sum += xws[idx];
  h1[idx] = sum * dd + cb[c] + x[idx];
}

// ---------------- BN helpers ----------------

__global__ __launch_bounds__(256) void bn_stats_k(const float* __restrict__ X,
    float* __restrict__ sums, float* __restrict__ sumsq) {
  int t = threadIdx.x;
  int c = t & 127, rg = t >> 7;
  int r0 = blockIdx.x * 64;
  float s = 0.f, sq = 0.f;
  for (int i = 0; i < 32; ++i) {
    float v = X[(size_t)(r0 + rg + 2 * i) * CC + c];
    s += v; sq += v * v;
  }
  atomicAdd(&sums[c], s);
  atomicAdd(&sumsq[c], sq);
}

__global__ __launch_bounds__(256) void combine_k(const float* __restrict__ h1, const float* __restrict__ h2,
    const float* __restrict__ st, const float* __restrict__ g1, const float* __restrict__ be1,
    const float* __restrict__ g2, const float* __restrict__ be2, float* __restrict__ out) {
  int idx = blockIdx.x * 256 + threadIdx.x;
  int c = idx & 127;
  float mu1 = st[c] * (1.f / NN);
  float var1 = st[128 + c] * (1.f / NN) - mu1 * mu1;
  float sc1 = g1[c] * rsqrtf(var1 + 1e-5f);
  float sh1 = be1[c] - mu1 * sc1;
  float mu2 = st[256 + c] * (1.f / NN);
  float var2 = st[384 + c] * (1.f / NN) - mu2 * mu2;
  float sc2 = g2[c] * rsqrtf(var2 + 1e-5f);
  float sh2 = be2[c] - mu2 * sc2;
  out[idx] = sc1 * h1[idx] + sh1 + sc2 * h2[idx] + sh2;
}

__global__ __launch_bounds__(256) void bn_apply_k(const float* __restrict__ h, const float* __restrict__ st,
    const float* __restrict__ g3, const float* __restrict__ be3, float* __restrict__ out) {
  int idx = blockIdx.x * 256 + threadIdx.x;
  int c = idx & 127;
  float mu = st[512 + c] * (1.f / NN);
  float var = st[640 + c] * (1.f / NN) - mu * mu;
  float sc = g3[c] * rsqrtf(var + 1e-5f);
  float sh = be3[c] - mu * sc;
  out[idx] = sc * h[idx] + sh;
}

// ---------------- fp32 GEMM ----------------
__global__ __launch_bounds__(256) void gemm_k(const float* __restrict__ A, const float* __restrict__ W,
    const float* __restrict__ bias, const float* __restrict__ resid, const float* __restrict__ dscale,
    float* __restrict__ out, int M, int N, int K, float scale, int relu) {
  __shared__ float As[64 * 132];
  __shared__ float Ws[128 * 64];
  int t = threadIdx.x;
  int ty = t >> 4, tx = t & 15;
  int row0 = blockIdx.x * 64, n0 = blockIdx.y * 64;
  float acc[4][4] = {};
  for (int kc = 0; kc < K; kc += 128) {
#pragma unroll
    for (int j = 0; j < 8; ++j) {
      int f = t + 256 * j;
      int r = f >> 5, c4 = f & 31;
      *(float4*)(As + r * 132 + c4 * 4) = *(const float4*)(A + (size_t)(row0 + r) * K + kc + c4 * 4);
    }
#pragma unroll
    for (int j = 0; j < 8; ++j) {
      int f = t + 256 * j;
      int kr = f >> 4, c4 = f & 15;
      *(float4*)(Ws + kr * 64 + c4 * 4) = *(const float4*)(W + (size_t)(kc + kr) * N + n0 + c4 * 4);
    }
    __syncthreads();
    for (int k0 = 0; k0 < 128; k0 += 4) {
      float a[4][4], b[4][4];
#pragma unroll
      for (int i = 0; i < 4; ++i) {
        float4 t4 = *(const float4*)(As + (4 * ty + i) * 132 + k0);
        a[i][0] = t4.x; a[i][1] = t4.y; a[i][2] = t4.z; a[i][3] = t4.w;
      }
#pragma unroll
      for (int kk = 0; kk < 4; ++kk) {
        float4 t4 = *(const float4*)(Ws + (k0 + kk) * 64 + 4 * tx);
        b[kk][0] = t4.x; b[kk][1] = t4.y; b[kk][2] = t4.z; b[kk][3] = t4.w;
      }
#pragma unroll
      for (int kk = 0; kk < 4; ++kk)
#pragma unroll
        for (int i = 0; i < 4; ++i)
#pragma unroll
          for (int j = 0; j < 4; ++j)
            acc[i][j] += a[i][kk] * b[kk][j];
    }
    __syncthreads();
  }
  float4 bv = make_float4(0.f, 0.f, 0.f, 0.f);
  if (bias) bv = *(const float4*)(bias + n0 + 4 * tx);
#pragma unroll
  for (int i = 0; i < 4; ++i) {
    int row = row0 + 4 * ty + i;
    float ds = dscale ? dscale[row] : 1.f;
    float4 r;
    r.x = (acc[i][0] + bv.x) * scale * ds;
    r.y = (acc[i][1] + bv.y) * scale * ds;
    r.z = (acc[i][2] + bv.z) * scale * ds;
    r.w = (acc[i][3] + bv.w) * scale * ds;
    if (relu) { r.x = fmaxf(r.x, 0.f); r.y = fmaxf(r.y, 0.f); r.z = fmaxf(r.z, 0.f); r.w = fmaxf(r.w, 0.f); }
    size_t o = (size_t)row * N + n0 + 4 * tx;
    if (resid) {
      float4 rv = *(const float4*)(resid + o);
      r.x += rv.x; r.y += rv.y; r.z += rv.z; r.w += rv.w;
    }
    *(float4*)(out + o) = r;
  }
}

// ---------------- flash attention: latency-bound fix — 4 waves/SIMD ----------------
// v2: 1 q-row/thread (8q x 8h per wave), 4-key chunks, LDS 10KB/block (2 x [K 2KB|V 2KB|bias 1KB])
// -> 16 single-wave blocks/CU (LDS-exact 160KB), grid 4096 fully resident, 4 waves/SIMD.
// Splits stay 4 -> partial layout + merge unchanged.
// XCD swizzle: l = ((orig&7)<<9)|(orig>>3) makes all 64 q-tiles of one (b,split) co-resident
// on one XCD (K/V working set 1MB per XCD L2) despite the 4x K/V re-read from more q-tiles.
// K/V LDS reads are q-broadcast (8 lanes share); h vs h+4 2-way alias is free; j-rotation keeps
// h vs h+2 off the same bank. Bias staged 1KB/chunk with q-rotation on kk (source pre-swizzled,
// linear LDS dest as global_load_lds requires); read back conflict-free.
// No max-tracking: scores O(9) << 88, raw exp safe (unchanged numerics).
__global__ __launch_bounds__(64, 4) void attn_k(const float* __restrict__ Q, const float* __restrict__ K,
    const float* __restrict__ V, const float* __restrict__ bias,
    unsigned* __restrict__ pA, unsigned* __restrict__ pB, float* __restrict__ lbuf) {
  __shared__ float SM[2][1280];   // per buf: K[0..512) V[512..1024) B[1024..1280)
  const int t = threadIdx.x;
  const int orig = blockIdx.x;
  const int lb = ((orig & 7) << 9) | (orig >> 3);   // bijective XCD-contiguous swizzle (4096 % 8 == 0)
  const int grp = lb >> 6;        // (b*4 + s), 64 groups
  const int qt = lb & 63;         // 64 q-tiles of 8 rows
  const int b = grp >> 2;
  const int s = grp & 3;
  const int q = t >> 3;           // this thread's q row within tile
  const int h = t & 7;
  const int node_t = b * 512 + qt * 8;
  const int node = node_t + q;
  const int key0 = s * 128;
  const size_t kvb = ((size_t)b * 512 + key0) * CC;
  const float* bbase = bias + ((size_t)node_t * 512 + key0) * 8;

  // rotated Q fragments: qf[j] holds element group (j+h)&3 of row node, head h
  float4 qf[4];
#pragma unroll
  for (int j = 0; j < 4; ++j)
    qf[j] = *(const float4*)(Q + (size_t)node * CC + h * 16 + (((j + h) & 3) << 2));

  float4 acc[4];
  float lsum = 0.f;
#pragma unroll
  for (int j = 0; j < 4; ++j) acc[j] = make_float4(0.f, 0.f, 0.f, 0.f);

  auto stage = [&](int ch, int bf) {
    const float* kg = K + kvb + ch * 512;     // 4 keys x 128 floats
    const float* vg = V + kvb + ch * 512;
    float* ksl = &SM[bf][0];
    float* vsl = &SM[bf][512];
    float* bsl = &SM[bf][1024];
#pragma unroll
    for (int i = 0; i < 2; ++i) {
      glds16(kg + i * 256 + t * 4, ksl + i * 256);
      glds16(vg + i * 256 + t * 4, vsl + i * 256);
    }
    // bias: lane t = (ql,kkp,hq); LDS slot [ql*32 + kkp*8 + hq*4]; source kk = (kkp-ql)&3
    {
      int ql = t >> 3, kkp = (t >> 1) & 3, hq = t & 1;
      int kks = (kkp - ql) & 3;
      glds16(bbase + (size_t)ql * 4096 + (size_t)(ch * 4 + kks) * 8 + hq * 4, bsl);
    }
  };

  stage(0, 0);
  for (int ch = 0; ch < 32; ++ch) {
    int bf = ch & 1;
    if (ch + 1 < 32) stage(ch + 1, bf ^ 1);
    asm volatile("" ::: "memory");
    if (ch + 1 < 32) __builtin_amdgcn_s_waitcnt(0x0F75);  // vmcnt(5): this chunk done, next 5 in flight
    else             __builtin_amdgcn_s_waitcnt(0x0F70);  // vmcnt(0)
    asm volatile("" ::: "memory");
    const float* ksl = &SM[bf][0];
    const float* vsl = &SM[bf][512];
    const float* bsl = &SM[bf][1024];
#pragma unroll
    for (int kk = 0; kk < 4; ++kk) {
      float4 kr[4], vr[4];
#pragma unroll
      for (int j = 0; j < 4; ++j) {
        int off = kk * 128 + h * 16 + (((j + h) & 3) << 2);
        kr[j] = *(const float4*)(ksl + off);
        vr[j] = *(const float4*)(vsl + off);
      }
      float sc = bsl[q * 32 + (((kk + q) & 3) << 3) + h];
#pragma unroll
      for (int j = 0; j < 4; ++j)
        sc += qf[j].x * kr[j].x + qf[j].y * kr[j].y
            + qf[j].z * kr[j].z + qf[j].w * kr[j].w;
      float p = __expf(sc);
      lsum += p;
#pragma unroll
      for (int j = 0; j < 4; ++j) {
        acc[j].x += p * vr[j].x; acc[j].y += p * vr[j].y;
        acc[j].z += p * vr[j].z; acc[j].w += p * vr[j].w;
      }
    }
  }

  // write bf16 raw-sum partials (un-rotate group order) + l
  unsigned* pbase = (s < 2 ? pA : pB) + (size_t)(s & 1) * (NN * CC / 2);
  int slot = (node * 8 + h) * 8;
  unsigned u[8];
#pragma unroll
  for (int g = 0; g < 4; ++g) {
    int j = (g - h) & 3;
    u[2 * g]     = f2bf_pack(acc[j].x, acc[j].y);
    u[2 * g + 1] = f2bf_pack(acc[j].z, acc[j].w);
  }
  *(uint4*)(pbase + slot)     = make_uint4(u[0], u[1], u[2], u[3]);
  *(uint4*)(pbase + slot + 4) = make_uint4(u[4], u[5], u[6], u[7]);
  lbuf[s * 65536 + node * 8 + h] = lsum;
}

__global__ __launch_bounds__(256) void attn_merge_k(const unsigned* __restrict__ pA,
    const unsigned* __restrict__ pB, const float* __restrict__ lbuf, float* __restrict__ out) {
  int i = blockIdx.x * 256 + threadIdx.x;   // (node,h), 65536 total
  float L = lbuf[i] + lbuf[65536 + i] + lbuf[131072 + i] + lbuf[196608 + i];
  float inv = 1.f / L;
  float o[16];
#pragma unroll
  for (int d = 0; d < 16; ++d) o[d] = 0.f;
#pragma unroll
  for (int s = 0; s < 4; ++s) {
    const unsigned* pb = (s < 2 ? pA : pB) + (size_t)(s & 1) * (NN * CC / 2) + (size_t)i * 8;
    uint4 a = *(const uint4*)pb;
    uint4 b = *(const uint4*)(pb + 4);
    unsigned u[8] = {a.x, a.y, a.z, a.w, b.x, b.y, b.z, b.w};
#pragma unroll
    for (int j = 0; j < 8; ++j) {
      o[2*j]   += bf_lo(u[j]);
      o[2*j+1] += bf_hi(u[j]);
    }
  }
  float* po = out + (size_t)i * 16;
#pragma unroll
  for (int j = 0; j < 4; ++j)
    *(float4*)(po + 4 * j) = make_float4(o[4*j] * inv, o[4*j+1] * inv, o[4*j+2] * inv, o[4*j+3] * inv);
}

// ---------------- launcher ----------------

extern "C" void kernel_launch(void* const* d_in, const int* in_sizes, int n_in,
                              void* d_out, int out_size, void* d_ws, size_t ws_size,
                              hipStream_t stream) {
  const float* x      = (const float*)d_in[0];
  const int*   ei     = (const int*)d_in[1];
  const float* bias   = (const float*)d_in[3];
  const float* conv_w = (const float*)d_in[4];
  const float* conv_b = (const float*)d_in[5];
  const float* wq = (const float*)d_in[6];
  const float* bq = (const float*)d_in[7];
  const float* wk = (const float*)d_in[8];
  const float* bk = (const float*)d_in[9];
  const float* wv = (const float*)d_in[10];
  const float* bv = (const float*)d_in[11];
  const float* wo = (const float*)d_in[12];
  const float* bo = (const float*)d_in[13];
  const float* w1 = (const float*)d_in[14];
  const float* b1 = (const float*)d_in[15];
  const float* w2 = (const float*)d_in[16];
  const float* b2 = (const float*)d_in[17];
  const float* g1 = (const float*)d_in[18];
  const float* be1 = (const float*)d_in[19];
  const float* g2 = (const float*)d_in[20];
  const float* be2 = (const float*)d_in[21];
  const float* g3 = (const float*)d_in[22];
  const float* be3 = (const float*)d_in[23];
  int E = in_sizes[1] / 2;

  float* ws = (float*)d_ws;
  const size_t NC = (size_t)NN * CC;
  float* xw     = ws;            // conv xws; then bf16 partials s=0,1
  float* h1pre  = ws + NC;
  float* qb     = ws + 2 * NC;
  float* kb     = ws + 3 * NC;
  float* vb     = ws + 4 * NC;
  float* h2pre  = ws + 5 * NC;   // bf16 partials s=2,3 during attn; then wo-gemm out
  float* outbuf = ws + 6 * NC;   // merged att; then combine out (MLP input)
  float* hid    = ws + 2 * NC;   // reuse qb+kb after attention
  float* h3pre  = ws + 4 * NC;   // reuse vb after attention
  float* st     = ws + 7 * NC;   // 768 floats BN sums
  float* dinv   = ws + 7 * NC + 768;
  int*   degi     = (int*)(ws + 7 * NC + 768 + NN);
  int*   rowstart = degi + NN;
  int*   cursor   = rowstart + NN + 1;
  int*   col      = cursor + NN;
  float* lbuf     = (float*)(col + E);   // 4 * 65536 floats

  hipMemsetAsync(degi, 0, NN * sizeof(int), stream);
  hipMemsetAsync(st, 0, 768 * sizeof(float), stream);

  // ---- GCN branch
  count_deg_int_k<<<(E + 255) / 256, 256, 0, stream>>>(ei + E, degi, E);
  dinv_k<<<NN / 256, 256, 0, stream>>>(degi, dinv, NN);
  scan_k<<<1, 256, 0, stream>>>(degi, rowstart, cursor);
  bucket_k<<<(E + 255) / 256, 256, 0, stream>>>(ei, ei + E, cursor, col, E);
  gemm_k<<<dim3(NN / 64, 2), 256, 0, stream>>>(x, conv_w, nullptr, nullptr, dinv, xw, NN, CC, CC, 1.f, 0);
  gather_k<<<NN / 2, 256, 0, stream>>>(rowstart, col, xw, dinv, conv_b, x, h1pre);
  bn_stats_k<<<NN / 64, 256, 0, stream>>>(h1pre, st + 0, st + 128);

  // ---- attention branch
  gemm_k<<<dim3(NN / 64, 2), 256, 0, stream>>>(x, wq, bq, nullptr, nullptr, qb, NN, CC, CC, 0.25f, 0);
  gemm_k<<<dim3(NN / 64, 2), 256, 0, stream>>>(x, wk, bk, nullptr, nullptr, kb, NN, CC, CC, 1.f, 0);
  gemm_k<<<dim3(NN / 64, 2), 256, 0, stream>>>(x, wv, bv, nullptr, nullptr, vb, NN, CC, CC, 1.f, 0);
  attn_k<<<4096, 64, 0, stream>>>(qb, kb, vb, bias, (unsigned*)xw, (unsigned*)h2pre, lbuf);
  attn_merge_k<<<65536 / 256, 256, 0, stream>>>((unsigned*)xw, (unsigned*)h2pre, lbuf, outbuf);
  gemm_k<<<dim3(NN / 64, 2), 256, 0, stream>>>(outbuf, wo, bo, x, nullptr, h2pre, NN, CC, CC, 1.f, 0);
  bn_stats_k<<<NN / 64, 256, 0, stream>>>(h2pre, st + 256, st + 384);

  // ---- combine + MLP (BN finalizes fused)
  combine_k<<<NC / 256, 256, 0, stream>>>(h1pre, h2pre, st, g1, be1, g2, be2, outbuf);
  gemm_k<<<dim3(NN / 64, 4), 256, 0, stream>>>(outbuf, w1, b1, nullptr, nullptr, hid, NN, 2 * CC, CC, 1.f, 1);
  gemm_k<<<dim3(NN / 64, 2), 256, 0, stream>>>(hid, w2, b2, outbuf, nullptr, h3pre, NN, CC, 2 * CC, 1.f, 0);
  bn_stats_k<<<NN / 64, 256, 0, stream>>>(h3pre, st + 512, st + 640);
  bn_apply_k<<<NC / 256, 256, 0, stream>>>(h3pre, st, g3, be3, (float*)d_out);
}